// Round 11
// baseline (1649.080 us; speedup 1.0000x reference)
//
#include <hip/hip_runtime.h>
#include <math.h>

#define D 128
#define EPSF 1e-9f
#define KST 136   // padded bf16 row stride for keys/aggn in LDS (odd dword stride)

typedef __bf16 bf16x8 __attribute__((ext_vector_type(8)));
typedef float  f32x4  __attribute__((ext_vector_type(4)));
typedef float  f32x2  __attribute__((ext_vector_type(2)));

static __device__ __forceinline__ float bf2f(unsigned short h) {
    union { unsigned int u; float f; } c; c.u = ((unsigned int)h) << 16;
    return c.f;
}
static __device__ __forceinline__ unsigned short f2bf(float f) {
    union { float f; unsigned int u; } c; c.f = f;
    unsigned int u = c.u + 0x7fffu + ((c.u >> 16) & 1u);
    return (unsigned short)(u >> 16);
}

// ---------------- W transpose to bf16 (tiny, once) ----------------
__global__ __launch_bounds__(256) void transpose_w_kernel(
    const float* __restrict__ attn_W, const float* __restrict__ gate_W,
    __bf16* __restrict__ wta, __bf16* __restrict__ wtg)
{
    int i = blockIdx.x * 256 + threadIdx.x;
    if (i < 128 * 128) {
        int k = i >> 7, n = i & 127;
        wta[n * 128 + k] = (__bf16)attn_W[i];
    }
    if (i < 256 * 128) {
        int k = i >> 7, n = i & 127;
        wtg[n * 256 + k] = (__bf16)gate_W[i];
    }
}

// ---------------- CSR build ----------------
__global__ __launch_bounds__(256) void hist_kernel(
    const int* __restrict__ idx3, const int* __restrict__ idx5,
    int* __restrict__ cnt, int E3, int E)
{
    int e = blockIdx.x * 256 + threadIdx.x;
    if (e >= E) return;
    int n = (e < E3) ? idx3[e] : idx5[e - E3];
    atomicAdd(&cnt[n], 1);
}

__global__ __launch_bounds__(256) void scan1_kernel(
    const int* __restrict__ cnt, int* __restrict__ row_start,
    int* __restrict__ bsum, int N)
{
    __shared__ int tsum[256];
    const int t = threadIdx.x;
    const int base = blockIdx.x * 1024;
    const int i0 = base + t * 4;
    int v0 = 0, v1 = 0, v2 = 0, v3 = 0;
    if (i0 + 0 < N) v0 = cnt[i0 + 0];
    if (i0 + 1 < N) v1 = cnt[i0 + 1];
    if (i0 + 2 < N) v2 = cnt[i0 + 2];
    if (i0 + 3 < N) v3 = cnt[i0 + 3];
    int s = v0 + v1 + v2 + v3;
    tsum[t] = s;
    __syncthreads();
    int val = s;
    for (int off = 1; off < 256; off <<= 1) {
        int tmp = (t >= off) ? tsum[t - off] : 0;
        __syncthreads();
        val += tmp; tsum[t] = val;
        __syncthreads();
    }
    int excl = val - s;
    if (i0 + 0 < N) row_start[i0 + 0] = excl;            excl += v0;
    if (i0 + 1 < N) row_start[i0 + 1] = excl;            excl += v1;
    if (i0 + 2 < N) row_start[i0 + 2] = excl;            excl += v2;
    if (i0 + 3 < N) row_start[i0 + 3] = excl;
    if (t == 255) bsum[blockIdx.x] = val;
}

__global__ __launch_bounds__(1024) void scan2_kernel(int* __restrict__ bsum, int nb)
{
    __shared__ int sh[1024];
    const int t = threadIdx.x;
    int v = (t < nb) ? bsum[t] : 0;
    sh[t] = v;
    __syncthreads();
    int val = v;
    for (int off = 1; off < 1024; off <<= 1) {
        int tmp = (t >= off) ? sh[t - off] : 0;
        __syncthreads();
        val += tmp; sh[t] = val;
        __syncthreads();
    }
    if (t < nb) bsum[t] = val - v;
}

__global__ __launch_bounds__(256) void scan3_kernel(
    int* __restrict__ row_start, const int* __restrict__ bsum, int N, int E)
{
    int i = blockIdx.x * 256 + threadIdx.x;
    if (i < N)       row_start[i] += bsum[i >> 10];
    else if (i == N) row_start[N] = E;
}

__global__ __launch_bounds__(256) void scatter_kernel(
    const int* __restrict__ idx3, const int* __restrict__ idx5,
    const int* __restrict__ row_start, int* __restrict__ cursor,
    int* __restrict__ edge_ids, int E3, int E)
{
    int e = blockIdx.x * 256 + threadIdx.x;
    if (e >= E) return;
    int n = (e < E3) ? idx3[e] : idx5[e - E3];
    int p = row_start[n] + atomicAdd(&cursor[n], 1);
    edge_ids[p] = e;
}

// ---------------- fused keys + attention-aggregate + gate ----------------
// Each wave owns 16 consecutive nodes. Their CSR edges form ONE contiguous
// range of edge_ids. No __syncthreads anywhere (all LDS regions wave-private).
// A: keys = bf16(prev@Wa + b) via MFMA -> LDS (padded stride KST).
// B: walk edge range in batches of 8: gather v (8B/lane coalesced, nontemporal),
//    key dot from LDS, 6-shfl reduce, exp, LDS fp32 atomics into agg[16][128].
// C: normalize -> aggn bf16 overwrites keys LDS -> gate MFMA -> blend -> d_out.
__global__ __launch_bounds__(256) void fused_kernel(
    const float* __restrict__ prev,
    const float* __restrict__ occ3, const float* __restrict__ occ5,
    const __bf16* __restrict__ wta, const __bf16* __restrict__ wtg,
    const float* __restrict__ attn_b, const float* __restrict__ gate_b,
    const int* __restrict__ row_start, const int* __restrict__ edge_ids,
    float* __restrict__ out, int E3, int N)
{
    __shared__ __bf16 kag[4][16 * KST];   // 17.4 KB: keys, later aggn
    __shared__ float  agf[4][16 * D];     // 32 KB: fp32 accumulators
    __shared__ float  dnf[4][16];         // denominators

    const int lane = threadIdx.x & 63;
    const int wid  = threadIdx.x >> 6;
    const int m0 = (blockIdx.x * 4 + wid) * 16;
    if (m0 >= N) return;
    const int lm = lane & 15;
    const int lg = lane >> 4;

    __bf16* kl = kag[wid];
    float*  af = agf[wid];
    float*  dn = dnf[wid];

    for (int i = lane; i < 16 * D; i += 64) af[i] = 0.f;
    if (lane < 16) dn[lane] = 0.f;

    // ---------- stage A: keys ----------
    int arow = m0 + lm; if (arow >= N) arow = m0;
    const float* ap = prev + (size_t)arow * D + lg * 8;
    {
        f32x4 acc[8] = {};
        #pragma unroll
        for (int kk = 0; kk < 4; ++kk) {
            float4 a0 = *(const float4*)(ap + kk * 32);
            float4 a1 = *(const float4*)(ap + kk * 32 + 4);
            bf16x8 afr;
            afr[0] = (__bf16)a0.x; afr[1] = (__bf16)a0.y; afr[2] = (__bf16)a0.z; afr[3] = (__bf16)a0.w;
            afr[4] = (__bf16)a1.x; afr[5] = (__bf16)a1.y; afr[6] = (__bf16)a1.z; afr[7] = (__bf16)a1.w;
            const int k0 = kk * 32;
            #pragma unroll
            for (int t = 0; t < 8; ++t) {
                bf16x8 bfr = *(const bf16x8*)(wta + (size_t)(t * 16 + lm) * 128 + k0 + lg * 8);
                acc[t] = __builtin_amdgcn_mfma_f32_16x16x32_bf16(afr, bfr, acc[t], 0, 0, 0);
            }
        }
        #pragma unroll
        for (int t = 0; t < 8; ++t) {
            float b = attn_b[t * 16 + lm];
            #pragma unroll
            for (int r = 0; r < 4; ++r)
                kl[(lg * 4 + r) * KST + t * 16 + lm] = (__bf16)(acc[t][r] + b);
        }
    }

    // ---------- stage B: edges ----------
    const int rs0 = row_start[m0];
    int hi = m0 + 16; if (hi > N) hi = N;
    const int re0 = row_start[hi];
    int bidx = m0 + (lane < 16 ? lane : 16); if (bidx > N) bidx = N;
    const int rsv = row_start[bidx];        // node-boundary values for search
    const float scale = 0.0883883476483184f;  // 1/sqrt(128)

    for (int base = rs0; base < re0; base += 64) {
        int cnt = re0 - base; if (cnt > 64) cnt = 64;
        int p = base + lane;
        int myid = (lane < cnt) ? edge_ids[p] : 0;
        int lo = 0;                          // largest i in [0,15] with rsv[i] <= p
        #pragma unroll
        for (int st = 8; st >= 1; st >>= 1) {
            int v = __shfl(rsv, lo + st);
            if (v <= p) lo += st;
        }

        for (int q0 = 0; q0 < cnt; q0 += 8) {
            f32x2 v[8]; int nl[8]; float s[8];
            #pragma unroll
            for (int j = 0; j < 8; ++j) {
                int e = __shfl(myid, q0 + j);
                nl[j] = __shfl(lo, q0 + j);
                const f32x2* vp = (e < E3)
                    ? (const f32x2*)(occ3 + (size_t)e * D)
                    : (const f32x2*)(occ5 + (size_t)(e - E3) * D);
                v[j] = __builtin_nontemporal_load(&vp[lane]);
            }
            #pragma unroll
            for (int j = 0; j < 8; ++j) {
                unsigned int kp = *(const unsigned int*)(kl + nl[j] * KST + 2 * lane);
                s[j] = v[j][0] * bf2f((unsigned short)(kp & 0xffffu))
                     + v[j][1] * bf2f((unsigned short)(kp >> 16));
            }
            #pragma unroll
            for (int sh = 32; sh >= 1; sh >>= 1) {
                #pragma unroll
                for (int j = 0; j < 8; ++j)
                    s[j] += __shfl_xor(s[j], sh);
            }
            #pragma unroll
            for (int j = 0; j < 8; ++j) {
                float ex = (q0 + j < cnt) ? __expf(s[j] * scale) : 0.f;
                atomicAdd(&af[nl[j] * D + 2 * lane],     ex * v[j][0]);
                atomicAdd(&af[nl[j] * D + 2 * lane + 1], ex * v[j][1]);
                if (lane == 0) atomicAdd(&dn[nl[j]], ex);
            }
        }
    }
    __threadfence_block();

    // ---------- normalize -> aggn (bf16) overwrites keys ----------
    #pragma unroll
    for (int i = 0; i < 16; ++i) {
        float inv = 1.0f / (dn[i] + EPSF);
        float x = af[i * D + 2 * lane] * inv;
        float y = af[i * D + 2 * lane + 1] * inv;
        unsigned int pk = (unsigned int)f2bf(x) | ((unsigned int)f2bf(y) << 16);
        *(unsigned int*)(kl + i * KST + 2 * lane) = pk;
    }

    // ---------- stage C: gate ----------
    f32x4 gacc[8] = {};
    #pragma unroll
    for (int kk = 0; kk < 4; ++kk) {
        float4 a0 = *(const float4*)(ap + kk * 32);
        float4 a1 = *(const float4*)(ap + kk * 32 + 4);
        bf16x8 afr;
        afr[0] = (__bf16)a0.x; afr[1] = (__bf16)a0.y; afr[2] = (__bf16)a0.z; afr[3] = (__bf16)a0.w;
        afr[4] = (__bf16)a1.x; afr[5] = (__bf16)a1.y; afr[6] = (__bf16)a1.z; afr[7] = (__bf16)a1.w;
        const int k0 = kk * 32;
        #pragma unroll
        for (int t = 0; t < 8; ++t) {
            bf16x8 bfr = *(const bf16x8*)(wtg + (size_t)(t * 16 + lm) * 256 + k0 + lg * 8);
            gacc[t] = __builtin_amdgcn_mfma_f32_16x16x32_bf16(afr, bfr, gacc[t], 0, 0, 0);
        }
    }
    #pragma unroll
    for (int kk = 0; kk < 4; ++kk) {
        bf16x8 afr = *(const bf16x8*)(kl + lm * KST + kk * 32 + lg * 8);
        const int k0 = 128 + kk * 32;
        #pragma unroll
        for (int t = 0; t < 8; ++t) {
            bf16x8 bfr = *(const bf16x8*)(wtg + (size_t)(t * 16 + lm) * 256 + k0 + lg * 8);
            gacc[t] = __builtin_amdgcn_mfma_f32_16x16x32_bf16(afr, bfr, gacc[t], 0, 0, 0);
        }
    }

    #pragma unroll
    for (int t = 0; t < 8; ++t) {
        float bc = gate_b[t * 16 + lm];
        #pragma unroll
        for (int r = 0; r < 4; ++r) {
            int row = m0 + lg * 4 + r;
            if (row < N) {
                size_t off = (size_t)row * D + t * 16 + lm;
                float c = gacc[t][r] + bc;
                float z = 1.0f / (1.0f + __expf(-c));
                float a = bf2f(*(const unsigned short*)(kl + (lg * 4 + r) * KST + t * 16 + lm));
                float pv = prev[off];
                out[off] = fmaf(z, a - pv, pv);
            }
        }
    }
}

extern "C" void kernel_launch(void* const* d_in, const int* in_sizes, int n_in,
                              void* d_out, int out_size, void* d_ws, size_t ws_size,
                              hipStream_t stream)
{
    const float* occ3   = (const float*)d_in[0];
    const int*   idx3   = (const int*)d_in[1];
    const float* occ5   = (const float*)d_in[2];
    const int*   idx5   = (const int*)d_in[3];
    const float* prev   = (const float*)d_in[4];
    const float* attn_W = (const float*)d_in[5];
    const float* attn_b = (const float*)d_in[6];
    const float* gate_W = (const float*)d_in[7];
    const float* gate_b = (const float*)d_in[8];

    const int N  = in_sizes[4] / D;
    const int E3 = in_sizes[1];
    const int E5 = in_sizes[3];
    const int E  = E3 + E5;

    // ws: row_start(N+1) | cnt(N) | cursor(N) | bsum(1025) | edge_ids(E) | wta | wtg
    int* row_start = (int*)d_ws;
    int* cnt       = row_start + (N + 1);
    int* cursor    = cnt + N;
    int* bsum      = cursor + N;
    int* edge_ids  = bsum + 1025;
    __bf16* wta    = (__bf16*)(edge_ids + E);
    __bf16* wtg    = wta + 128 * 128;

    float* out = (float*)d_out;

    (void)hipMemsetAsync(cnt, 0, (size_t)2 * N * sizeof(int), stream);  // cnt + cursor

    transpose_w_kernel<<<128, 256, 0, stream>>>(attn_W, gate_W, wta, wtg);

    const int nb = (N + 1023) / 1024;
    hist_kernel   <<<(E + 255) / 256, 256, 0, stream>>>(idx3, idx5, cnt, E3, E);
    scan1_kernel  <<<nb, 256, 0, stream>>>(cnt, row_start, bsum, N);
    scan2_kernel  <<<1, 1024, 0, stream>>>(bsum, nb);
    scan3_kernel  <<<(N + 256) / 256, 256, 0, stream>>>(row_start, bsum, N, E);
    scatter_kernel<<<(E + 255) / 256, 256, 0, stream>>>(idx3, idx5, row_start, cursor, edge_ids, E3, E);

    fused_kernel<<<(N + 63) / 64, 256, 0, stream>>>(
        prev, occ3, occ5, wta, wtg, attn_b, gate_b, row_start, edge_ids, out, E3, N);
}

// Round 13
// 707.114 us; speedup vs baseline: 2.3321x; 2.3321x over previous
//
#include <hip/hip_runtime.h>
#include <math.h>

#define D 128
#define EPSF 1e-9f

typedef __bf16 bf16x8 __attribute__((ext_vector_type(8)));
typedef float  f32x4  __attribute__((ext_vector_type(4)));
typedef float  f32x2  __attribute__((ext_vector_type(2)));

static __device__ __forceinline__ float bf2f(unsigned short h) {
    union { unsigned int u; float f; } c; c.u = ((unsigned int)h) << 16;
    return c.f;
}
static __device__ __forceinline__ unsigned short f2bf(float f) {
    union { float f; unsigned int u; } c; c.f = f;
    unsigned int u = c.u + 0x7fffu + ((c.u >> 16) & 1u);
    return (unsigned short)(u >> 16);
}

// ---------------- W transpose to bf16 (tiny, once) ----------------
__global__ __launch_bounds__(256) void transpose_w_kernel(
    const float* __restrict__ attn_W, const float* __restrict__ gate_W,
    __bf16* __restrict__ wta, __bf16* __restrict__ wtg)
{
    int i = blockIdx.x * 256 + threadIdx.x;
    if (i < 128 * 128) {
        int k = i >> 7, n = i & 127;
        wta[n * 128 + k] = (__bf16)attn_W[i];
    }
    if (i < 256 * 128) {
        int k = i >> 7, n = i & 127;
        wtg[n * 256 + k] = (__bf16)gate_W[i];
    }
}

// ---------------- keys = bf16( prev @ attn_W + attn_b ), MFMA ----------------
__global__ __launch_bounds__(256) void keys_mfma_kernel(
    const float* __restrict__ prev, const __bf16* __restrict__ wta,
    const float* __restrict__ attn_b, unsigned short* __restrict__ keysb, int N)
{
    const int lane = threadIdx.x & 63;
    const int wid  = threadIdx.x >> 6;
    const int m0 = (blockIdx.x * 4 + wid) * 16;
    if (m0 >= N) return;
    const int lm = lane & 15;
    const int lg = lane >> 4;

    int arow = m0 + lm; if (arow >= N) arow = m0;
    const float* ap = prev + (size_t)arow * D + lg * 8;

    f32x4 acc[8] = {};
    #pragma unroll
    for (int kk = 0; kk < 4; ++kk) {
        float4 a0 = *(const float4*)(ap + kk * 32);
        float4 a1 = *(const float4*)(ap + kk * 32 + 4);
        bf16x8 af;
        af[0] = (__bf16)a0.x; af[1] = (__bf16)a0.y; af[2] = (__bf16)a0.z; af[3] = (__bf16)a0.w;
        af[4] = (__bf16)a1.x; af[5] = (__bf16)a1.y; af[6] = (__bf16)a1.z; af[7] = (__bf16)a1.w;
        const int k0 = kk * 32;
        #pragma unroll
        for (int t = 0; t < 8; ++t) {
            bf16x8 bf_ = *(const bf16x8*)(wta + (size_t)(t * 16 + lm) * 128 + k0 + lg * 8);
            acc[t] = __builtin_amdgcn_mfma_f32_16x16x32_bf16(af, bf_, acc[t], 0, 0, 0);
        }
    }
    __bf16* kb = (__bf16*)keysb;
    #pragma unroll
    for (int t = 0; t < 8; ++t) {
        float bcol = attn_b[t * 16 + lm];
        #pragma unroll
        for (int r = 0; r < 4; ++r) {
            int row = m0 + lg * 4 + r;
            if (row < N)
                kb[(size_t)row * D + t * 16 + lm] = (__bf16)(acc[t][r] + bcol);
        }
    }
}

// ---------------- CSR build ----------------
// hist also records each edge's rank within its node (atomicAdd return),
// making the scatter pass atomic-free.
__global__ __launch_bounds__(256) void hist_kernel(
    const int* __restrict__ idx3, const int* __restrict__ idx5,
    int* __restrict__ cnt, int* __restrict__ rank, int E3, int E)
{
    int e = blockIdx.x * 256 + threadIdx.x;
    if (e >= E) return;
    int n = (e < E3) ? idx3[e] : idx5[e - E3];
    rank[e] = atomicAdd(&cnt[n], 1);
}

__global__ __launch_bounds__(256) void scan1_kernel(
    const int* __restrict__ cnt, int* __restrict__ row_start,
    int* __restrict__ bsum, int N)
{
    __shared__ int tsum[256];
    const int t = threadIdx.x;
    const int base = blockIdx.x * 1024;
    const int i0 = base + t * 4;
    int v0 = 0, v1 = 0, v2 = 0, v3 = 0;
    if (i0 + 0 < N) v0 = cnt[i0 + 0];
    if (i0 + 1 < N) v1 = cnt[i0 + 1];
    if (i0 + 2 < N) v2 = cnt[i0 + 2];
    if (i0 + 3 < N) v3 = cnt[i0 + 3];
    int s = v0 + v1 + v2 + v3;
    tsum[t] = s;
    __syncthreads();
    int val = s;
    for (int off = 1; off < 256; off <<= 1) {
        int tmp = (t >= off) ? tsum[t - off] : 0;
        __syncthreads();
        val += tmp; tsum[t] = val;
        __syncthreads();
    }
    int excl = val - s;
    if (i0 + 0 < N) row_start[i0 + 0] = excl;            excl += v0;
    if (i0 + 1 < N) row_start[i0 + 1] = excl;            excl += v1;
    if (i0 + 2 < N) row_start[i0 + 2] = excl;            excl += v2;
    if (i0 + 3 < N) row_start[i0 + 3] = excl;
    if (t == 255) bsum[blockIdx.x] = val;
}

__global__ __launch_bounds__(1024) void scan2_kernel(int* __restrict__ bsum, int nb)
{
    __shared__ int sh[1024];
    const int t = threadIdx.x;
    int v = (t < nb) ? bsum[t] : 0;
    sh[t] = v;
    __syncthreads();
    int val = v;
    for (int off = 1; off < 1024; off <<= 1) {
        int tmp = (t >= off) ? sh[t - off] : 0;
        __syncthreads();
        val += tmp; sh[t] = val;
        __syncthreads();
    }
    if (t < nb) bsum[t] = val - v;
}

__global__ __launch_bounds__(256) void scan3_kernel(
    int* __restrict__ row_start, const int* __restrict__ bsum, int N, int E)
{
    int i = blockIdx.x * 256 + threadIdx.x;
    if (i < N)       row_start[i] += bsum[i >> 10];
    else if (i == N) row_start[N] = E;
}

__global__ __launch_bounds__(256) void scatter_kernel(
    const int* __restrict__ idx3, const int* __restrict__ idx5,
    const int* __restrict__ row_start, const int* __restrict__ rank,
    int* __restrict__ edge_ids, int E3, int E)
{
    int e = blockIdx.x * 256 + threadIdx.x;
    if (e >= E) return;
    int n = (e < E3) ? idx3[e] : idx5[e - E3];
    edge_ids[row_start[n] + rank[e]] = e;
}

// ---------------- per-node attention aggregate (R8 structure) ----------------
// one 64-lane wave per node, lane owns dims 2l,2l+1 (8B gather/lane).
// edge ids preloaded lane-parallel + shfl broadcast; masked batches of 8
// -> 8 independent gathers in flight, no serial tail. Minimal VGPR, no LDS:
// occupancy is the lever for this latency/random-DRAM-bound phase (R11 lesson).
__global__ __launch_bounds__(256) void agg_kernel(
    const float* __restrict__ occ3, const float* __restrict__ occ5,
    const unsigned short* __restrict__ keysb,
    const int* __restrict__ row_start, const int* __restrict__ edge_ids,
    unsigned int* __restrict__ aggb, int E3, int N)
{
    const int lane = threadIdx.x & 63;
    const int wid  = threadIdx.x >> 6;
    const int n = blockIdx.x * 4 + wid;
    if (n >= N) return;

    unsigned int kp = ((const unsigned int*)keysb)[(size_t)n * (D / 2) + lane];
    float kx = bf2f((unsigned short)(kp & 0xffffu));
    float ky = bf2f((unsigned short)(kp >> 16));

    const int rs = row_start[n];
    const int re = row_start[n + 1];
    const float scale = 0.0883883476483184f;   // 1/sqrt(128)

    float ax = 0.f, ay = 0.f, den = 0.f;

    for (int base = rs; base < re; base += 64) {
        const int left = re - base;
        const int cnt = left < 64 ? left : 64;
        int myid = (lane < cnt) ? edge_ids[base + lane] : 0;

        for (int j0 = 0; j0 < cnt; j0 += 8) {
            f32x2 v[8];
            #pragma unroll
            for (int j = 0; j < 8; ++j) {
                int e = __shfl(myid, j0 + j);
                const f32x2* vp = (e < E3)
                    ? (const f32x2*)(occ3 + (size_t)e * D)
                    : (const f32x2*)(occ5 + (size_t)(e - E3) * D);
                v[j] = __builtin_nontemporal_load(&vp[lane]);
            }
            float s[8];
            #pragma unroll
            for (int j = 0; j < 8; ++j)
                s[j] = v[j][0] * kx + v[j][1] * ky;
            #pragma unroll
            for (int sh = 32; sh >= 1; sh >>= 1) {
                #pragma unroll
                for (int j = 0; j < 8; ++j)
                    s[j] += __shfl_xor(s[j], sh);
            }
            #pragma unroll
            for (int j = 0; j < 8; ++j) {
                float ex = (j0 + j < cnt) ? __expf(s[j] * scale) : 0.f;
                den += ex;
                ax = fmaf(ex, v[j][0], ax);
                ay = fmaf(ex, v[j][1], ay);
            }
        }
    }

    float inv = 1.0f / (den + EPSF);
    unsigned int pack = (unsigned int)f2bf(ax * inv)
                      | ((unsigned int)f2bf(ay * inv) << 16);
    aggb[(size_t)n * (D / 2) + lane] = pack;
}

// ---------------- gate via MFMA ----------------
__global__ __launch_bounds__(256) void gate_mfma_kernel(
    const float* __restrict__ prev, const __bf16* __restrict__ aggb,
    const __bf16* __restrict__ wtg, const float* __restrict__ gate_b,
    float* __restrict__ out, int N)
{
    const int lane = threadIdx.x & 63;
    const int wid  = threadIdx.x >> 6;
    const int m0 = (blockIdx.x * 4 + wid) * 16;
    if (m0 >= N) return;
    const int lm = lane & 15;
    const int lg = lane >> 4;

    int arow = m0 + lm; if (arow >= N) arow = m0;
    const float*  aprev = prev + (size_t)arow * D + lg * 8;
    const __bf16* aagg  = aggb + (size_t)arow * D + lg * 8;

    f32x4 acc[8] = {};
    #pragma unroll
    for (int kk = 0; kk < 4; ++kk) {
        float4 a0 = *(const float4*)(aprev + kk * 32);
        float4 a1 = *(const float4*)(aprev + kk * 32 + 4);
        bf16x8 af;
        af[0] = (__bf16)a0.x; af[1] = (__bf16)a0.y; af[2] = (__bf16)a0.z; af[3] = (__bf16)a0.w;
        af[4] = (__bf16)a1.x; af[5] = (__bf16)a1.y; af[6] = (__bf16)a1.z; af[7] = (__bf16)a1.w;
        const int k0 = kk * 32;
        #pragma unroll
        for (int t = 0; t < 8; ++t) {
            bf16x8 bf_ = *(const bf16x8*)(wtg + (size_t)(t * 16 + lm) * 256 + k0 + lg * 8);
            acc[t] = __builtin_amdgcn_mfma_f32_16x16x32_bf16(af, bf_, acc[t], 0, 0, 0);
        }
    }
    #pragma unroll
    for (int kk = 0; kk < 4; ++kk) {
        bf16x8 af = *(const bf16x8*)(aagg + kk * 32);
        const int k0 = 128 + kk * 32;
        #pragma unroll
        for (int t = 0; t < 8; ++t) {
            bf16x8 bf_ = *(const bf16x8*)(wtg + (size_t)(t * 16 + lm) * 256 + k0 + lg * 8);
            acc[t] = __builtin_amdgcn_mfma_f32_16x16x32_bf16(af, bf_, acc[t], 0, 0, 0);
        }
    }

    const unsigned short* aggu = (const unsigned short*)aggb;
    #pragma unroll
    for (int t = 0; t < 8; ++t) {
        float bcol = gate_b[t * 16 + lm];
        #pragma unroll
        for (int r = 0; r < 4; ++r) {
            int row = m0 + lg * 4 + r;
            if (row < N) {
                size_t off = (size_t)row * D + t * 16 + lm;
                float c = acc[t][r] + bcol;
                float z = 1.0f / (1.0f + __expf(-c));
                float a = bf2f(aggu[off]);
                float p = prev[off];
                __builtin_nontemporal_store(fmaf(z, a - p, p), &out[off]);
            }
        }
    }
}

extern "C" void kernel_launch(void* const* d_in, const int* in_sizes, int n_in,
                              void* d_out, int out_size, void* d_ws, size_t ws_size,
                              hipStream_t stream)
{
    const float* occ3   = (const float*)d_in[0];
    const int*   idx3   = (const int*)d_in[1];
    const float* occ5   = (const float*)d_in[2];
    const int*   idx5   = (const int*)d_in[3];
    const float* prev   = (const float*)d_in[4];
    const float* attn_W = (const float*)d_in[5];
    const float* attn_b = (const float*)d_in[6];
    const float* gate_W = (const float*)d_in[7];
    const float* gate_b = (const float*)d_in[8];

    const int N  = in_sizes[4] / D;
    const int E3 = in_sizes[1];
    const int E5 = in_sizes[3];
    const int E  = E3 + E5;

    // ws: keysb(bf16 N*D) | aggb(bf16 N*D) | row_start(N+1) | cnt(N) | bsum(1025) | rank(E) | edge_ids(E) | wta | wtg
    unsigned short* keysb = (unsigned short*)d_ws;
    unsigned int*   aggb  = (unsigned int*)(keysb + (size_t)N * D);
    int* row_start = (int*)((unsigned short*)aggb + (size_t)N * D);
    int* cnt       = row_start + (N + 1);
    int* bsum      = cnt + N;
    int* rank      = bsum + 1025;
    int* edge_ids  = rank + E;
    __bf16* wta    = (__bf16*)(edge_ids + E);
    __bf16* wtg    = wta + 128 * 128;

    float* out = (float*)d_out;

    (void)hipMemsetAsync(cnt, 0, (size_t)N * sizeof(int), stream);

    transpose_w_kernel<<<128, 256, 0, stream>>>(attn_W, gate_W, wta, wtg);

    const int nb = (N + 1023) / 1024;
    hist_kernel   <<<(E + 255) / 256, 256, 0, stream>>>(idx3, idx5, cnt, rank, E3, E);
    scan1_kernel  <<<nb, 256, 0, stream>>>(cnt, row_start, bsum, N);
    scan2_kernel  <<<1, 1024, 0, stream>>>(bsum, nb);
    scan3_kernel  <<<(N + 256) / 256, 256, 0, stream>>>(row_start, bsum, N, E);
    scatter_kernel<<<(E + 255) / 256, 256, 0, stream>>>(idx3, idx5, row_start, rank, edge_ids, E3, E);

    keys_mfma_kernel<<<(N + 63) / 64, 256, 0, stream>>>(prev, wta, attn_b, keysb, N);

    agg_kernel<<<(N + 3) / 4, 256, 0, stream>>>(occ3, occ5, keysb, row_start, edge_ids, aggb, E3, N);

    gate_mfma_kernel<<<(N + 63) / 64, 256, 0, stream>>>(prev, (const __bf16*)aggb, wtg, gate_b, out, N);
}

// Round 16
// 667.775 us; speedup vs baseline: 2.4695x; 1.0589x over previous
//
#include <hip/hip_runtime.h>
#include <math.h>

#define D 128
#define EPSF 1e-9f

typedef __bf16 bf16x8 __attribute__((ext_vector_type(8)));
typedef float  f32x4  __attribute__((ext_vector_type(4)));
typedef float  f32x2  __attribute__((ext_vector_type(2)));

static __device__ __forceinline__ float bf2f(unsigned short h) {
    union { unsigned int u; float f; } c; c.u = ((unsigned int)h) << 16;
    return c.f;
}
static __device__ __forceinline__ unsigned short f2bf(float f) {
    union { float f; unsigned int u; } c; c.f = f;
    unsigned int u = c.u + 0x7fffu + ((c.u >> 16) & 1u);
    return (unsigned short)(u >> 16);
}

// ---------------- fat kernel: W transpose (blocks 0..127) + histogram ----------------
__global__ __launch_bounds__(256) void hist_transpose_kernel(
    const float* __restrict__ attn_W, const float* __restrict__ gate_W,
    __bf16* __restrict__ wta, __bf16* __restrict__ wtg,
    const int* __restrict__ idx3, const int* __restrict__ idx5,
    int* __restrict__ cnt, int* __restrict__ rank, int E3, int E)
{
    int b = blockIdx.x;
    if (b < 128) {
        int i = b * 256 + threadIdx.x;          // i < 32768
        if (i < 128 * 128) {
            int k = i >> 7, n = i & 127;
            wta[n * 128 + k] = (__bf16)attn_W[i];
        }
        {   // gate_W is 256*128 = 32768 elements: every i valid
            int k = i >> 7, n = i & 127;
            wtg[n * 256 + k] = (__bf16)gate_W[i];
        }
    } else {
        int e = (b - 128) * 256 + threadIdx.x;
        if (e >= E) return;
        int n = (e < E3) ? idx3[e] : idx5[e - E3];
        rank[e] = atomicAdd(&cnt[n], 1);
    }
}

// ---------------- keys = bf16( prev @ attn_W + attn_b ), MFMA ----------------
// epilogue re-layouts acc through wave-private LDS -> coalesced ushort4 stores.
__global__ __launch_bounds__(256) void keys_mfma_kernel(
    const float* __restrict__ prev, const __bf16* __restrict__ wta,
    const float* __restrict__ attn_b, unsigned short* __restrict__ keysb, int N)
{
    __shared__ float stg[4][16 * D];    // 32 KB/block, wave-private slices
    const int lane = threadIdx.x & 63;
    const int wid  = threadIdx.x >> 6;
    const int m0 = (blockIdx.x * 4 + wid) * 16;
    if (m0 >= N) return;
    const int lm = lane & 15;
    const int lg = lane >> 4;

    int arow = m0 + lm; if (arow >= N) arow = m0;
    const float* ap = prev + (size_t)arow * D + lg * 8;

    f32x4 acc[8] = {};
    #pragma unroll
    for (int kk = 0; kk < 4; ++kk) {
        float4 a0 = *(const float4*)(ap + kk * 32);
        float4 a1 = *(const float4*)(ap + kk * 32 + 4);
        bf16x8 af;
        af[0] = (__bf16)a0.x; af[1] = (__bf16)a0.y; af[2] = (__bf16)a0.z; af[3] = (__bf16)a0.w;
        af[4] = (__bf16)a1.x; af[5] = (__bf16)a1.y; af[6] = (__bf16)a1.z; af[7] = (__bf16)a1.w;
        const int k0 = kk * 32;
        #pragma unroll
        for (int t = 0; t < 8; ++t) {
            bf16x8 bf_ = *(const bf16x8*)(wta + (size_t)(t * 16 + lm) * 128 + k0 + lg * 8);
            acc[t] = __builtin_amdgcn_mfma_f32_16x16x32_bf16(af, bf_, acc[t], 0, 0, 0);
        }
    }

    float* kw = stg[wid];
    #pragma unroll
    for (int t = 0; t < 8; ++t) {
        float bcol = attn_b[t * 16 + lm];
        #pragma unroll
        for (int r = 0; r < 4; ++r)
            kw[(lg * 4 + r) * D + t * 16 + lm] = acc[t][r] + bcol;
    }
    // wave-private LDS: no barrier needed (lgkmcnt ordering within wave)
    #pragma unroll
    for (int q = 0; q < 8; ++q) {
        int idx = q * 64 + lane;
        int ro = idx >> 5;
        int co = (idx & 31) * 4;
        int row = m0 + ro;
        if (row < N) {
            f32x4 c = *(const f32x4*)&kw[ro * D + co];
            ushort4 o;
            o.x = f2bf(c[0]); o.y = f2bf(c[1]); o.z = f2bf(c[2]); o.w = f2bf(c[3]);
            *(ushort4*)(keysb + (size_t)row * D + co) = o;
        }
    }
}

// ---------------- CSR scans ----------------
__global__ __launch_bounds__(256) void scan1_kernel(
    const int* __restrict__ cnt, int* __restrict__ row_start,
    int* __restrict__ bsum, int N)
{
    __shared__ int tsum[256];
    const int t = threadIdx.x;
    const int base = blockIdx.x * 1024;
    const int i0 = base + t * 4;
    int v0 = 0, v1 = 0, v2 = 0, v3 = 0;
    if (i0 + 0 < N) v0 = cnt[i0 + 0];
    if (i0 + 1 < N) v1 = cnt[i0 + 1];
    if (i0 + 2 < N) v2 = cnt[i0 + 2];
    if (i0 + 3 < N) v3 = cnt[i0 + 3];
    int s = v0 + v1 + v2 + v3;
    tsum[t] = s;
    __syncthreads();
    int val = s;
    for (int off = 1; off < 256; off <<= 1) {
        int tmp = (t >= off) ? tsum[t - off] : 0;
        __syncthreads();
        val += tmp; tsum[t] = val;
        __syncthreads();
    }
    int excl = val - s;
    if (i0 + 0 < N) row_start[i0 + 0] = excl;            excl += v0;
    if (i0 + 1 < N) row_start[i0 + 1] = excl;            excl += v1;
    if (i0 + 2 < N) row_start[i0 + 2] = excl;            excl += v2;
    if (i0 + 3 < N) row_start[i0 + 3] = excl;
    if (t == 255) bsum[blockIdx.x] = val;
}

__global__ __launch_bounds__(1024) void scan2_kernel(int* __restrict__ bsum, int nb)
{
    __shared__ int sh[1024];
    const int t = threadIdx.x;
    int v = (t < nb) ? bsum[t] : 0;
    sh[t] = v;
    __syncthreads();
    int val = v;
    for (int off = 1; off < 1024; off <<= 1) {
        int tmp = (t >= off) ? sh[t - off] : 0;
        __syncthreads();
        val += tmp; sh[t] = val;
        __syncthreads();
    }
    if (t < nb) bsum[t] = val - v;
}

__global__ __launch_bounds__(256) void scan3_kernel(
    int* __restrict__ row_start, const int* __restrict__ bsum, int N, int E)
{
    int i = blockIdx.x * 256 + threadIdx.x;
    if (i < N)       row_start[i] += bsum[i >> 10];
    else if (i == N) row_start[N] = E;
}

__global__ __launch_bounds__(256) void scatter_kernel(
    const int* __restrict__ idx3, const int* __restrict__ idx5,
    const int* __restrict__ row_start, const int* __restrict__ rank,
    int* __restrict__ edge_ids, int E3, int E)
{
    int e = blockIdx.x * 256 + threadIdx.x;
    if (e >= E) return;
    int n = (e < E3) ? idx3[e] : idx5[e - E3];
    edge_ids[row_start[n] + rank[e]] = e;
}

// ---------------- per-node attention aggregate ----------------
// one 64-lane wave per node, lane owns dims 2l,2l+1 (8B gather/lane).
// ids preloaded lane-parallel + shfl broadcast; masked batches of 8 ->
// 8 independent gathers in flight. Minimal VGPR, no LDS (occupancy = lever).
__global__ __launch_bounds__(256) void agg_kernel(
    const float* __restrict__ occ3, const float* __restrict__ occ5,
    const unsigned short* __restrict__ keysb,
    const int* __restrict__ row_start, const int* __restrict__ edge_ids,
    unsigned int* __restrict__ aggb, int E3, int N)
{
    const int lane = threadIdx.x & 63;
    const int wid  = threadIdx.x >> 6;
    const int n = blockIdx.x * 4 + wid;
    if (n >= N) return;

    unsigned int kp = ((const unsigned int*)keysb)[(size_t)n * (D / 2) + lane];
    float kx = bf2f((unsigned short)(kp & 0xffffu));
    float ky = bf2f((unsigned short)(kp >> 16));

    const int rs = row_start[n];
    const int re = row_start[n + 1];
    const float scale = 0.0883883476483184f;   // 1/sqrt(128)

    float ax = 0.f, ay = 0.f, den = 0.f;

    for (int base = rs; base < re; base += 64) {
        const int left = re - base;
        const int cnt = left < 64 ? left : 64;
        int myid = (lane < cnt) ? edge_ids[base + lane] : 0;

        for (int j0 = 0; j0 < cnt; j0 += 8) {
            f32x2 v[8];
            #pragma unroll
            for (int j = 0; j < 8; ++j) {
                int e = __shfl(myid, j0 + j);
                const f32x2* vp = (e < E3)
                    ? (const f32x2*)(occ3 + (size_t)e * D)
                    : (const f32x2*)(occ5 + (size_t)(e - E3) * D);
                v[j] = __builtin_nontemporal_load(&vp[lane]);
            }
            float s[8];
            #pragma unroll
            for (int j = 0; j < 8; ++j)
                s[j] = v[j][0] * kx + v[j][1] * ky;
            #pragma unroll
            for (int sh = 32; sh >= 1; sh >>= 1) {
                #pragma unroll
                for (int j = 0; j < 8; ++j)
                    s[j] += __shfl_xor(s[j], sh);
            }
            #pragma unroll
            for (int j = 0; j < 8; ++j) {
                float ex = (j0 + j < cnt) ? __expf(s[j] * scale) : 0.f;
                den += ex;
                ax = fmaf(ex, v[j][0], ax);
                ay = fmaf(ex, v[j][1], ay);
            }
        }
    }

    float inv = 1.0f / (den + EPSF);
    unsigned int pack = (unsigned int)f2bf(ax * inv)
                      | ((unsigned int)f2bf(ay * inv) << 16);
    aggb[(size_t)n * (D / 2) + lane] = pack;
}

// ---------------- gate via MFMA ----------------
// epilogue re-layouts z through wave-private LDS -> coalesced f32x4 blend.
__global__ __launch_bounds__(256) void gate_mfma_kernel(
    const float* __restrict__ prev, const __bf16* __restrict__ aggb,
    const __bf16* __restrict__ wtg, const float* __restrict__ gate_b,
    float* __restrict__ out, int N)
{
    __shared__ float stg[4][16 * D];    // 32 KB/block, wave-private slices
    const int lane = threadIdx.x & 63;
    const int wid  = threadIdx.x >> 6;
    const int m0 = (blockIdx.x * 4 + wid) * 16;
    if (m0 >= N) return;
    const int lm = lane & 15;
    const int lg = lane >> 4;

    int arow = m0 + lm; if (arow >= N) arow = m0;
    const float*  aprev = prev + (size_t)arow * D + lg * 8;
    const __bf16* aagg  = aggb + (size_t)arow * D + lg * 8;

    f32x4 acc[8] = {};
    #pragma unroll
    for (int kk = 0; kk < 4; ++kk) {
        float4 a0 = *(const float4*)(aprev + kk * 32);
        float4 a1 = *(const float4*)(aprev + kk * 32 + 4);
        bf16x8 af;
        af[0] = (__bf16)a0.x; af[1] = (__bf16)a0.y; af[2] = (__bf16)a0.z; af[3] = (__bf16)a0.w;
        af[4] = (__bf16)a1.x; af[5] = (__bf16)a1.y; af[6] = (__bf16)a1.z; af[7] = (__bf16)a1.w;
        const int k0 = kk * 32;
        #pragma unroll
        for (int t = 0; t < 8; ++t) {
            bf16x8 bf_ = *(const bf16x8*)(wtg + (size_t)(t * 16 + lm) * 256 + k0 + lg * 8);
            acc[t] = __builtin_amdgcn_mfma_f32_16x16x32_bf16(af, bf_, acc[t], 0, 0, 0);
        }
    }
    #pragma unroll
    for (int kk = 0; kk < 4; ++kk) {
        bf16x8 af = *(const bf16x8*)(aagg + kk * 32);
        const int k0 = 128 + kk * 32;
        #pragma unroll
        for (int t = 0; t < 8; ++t) {
            bf16x8 bf_ = *(const bf16x8*)(wtg + (size_t)(t * 16 + lm) * 256 + k0 + lg * 8);
            acc[t] = __builtin_amdgcn_mfma_f32_16x16x32_bf16(af, bf_, acc[t], 0, 0, 0);
        }
    }

    float* zw = stg[wid];
    #pragma unroll
    for (int t = 0; t < 8; ++t) {
        float bcol = gate_b[t * 16 + lm];
        #pragma unroll
        for (int r = 0; r < 4; ++r)
            zw[(lg * 4 + r) * D + t * 16 + lm] = acc[t][r] + bcol;
    }
    // wave-private LDS: no barrier needed
    const unsigned short* aggu = (const unsigned short*)aggb;
    #pragma unroll
    for (int q = 0; q < 8; ++q) {
        int idx = q * 64 + lane;
        int ro = idx >> 5;
        int co = (idx & 31) * 4;
        int row = m0 + ro;
        if (row < N) {
            size_t off = (size_t)row * D + co;
            f32x4 c = *(const f32x4*)&zw[ro * D + co];
            f32x4 p = *(const f32x4*)(prev + off);
            ushort4 a4 = *(const ushort4*)(aggu + off);
            f32x4 o;
            float z;
            z = 1.0f / (1.0f + __expf(-c[0])); o[0] = fmaf(z, bf2f(a4.x) - p[0], p[0]);
            z = 1.0f / (1.0f + __expf(-c[1])); o[1] = fmaf(z, bf2f(a4.y) - p[1], p[1]);
            z = 1.0f / (1.0f + __expf(-c[2])); o[2] = fmaf(z, bf2f(a4.z) - p[2], p[2]);
            z = 1.0f / (1.0f + __expf(-c[3])); o[3] = fmaf(z, bf2f(a4.w) - p[3], p[3]);
            __builtin_nontemporal_store(o, (f32x4*)(out + off));
        }
    }
}

extern "C" void kernel_launch(void* const* d_in, const int* in_sizes, int n_in,
                              void* d_out, int out_size, void* d_ws, size_t ws_size,
                              hipStream_t stream)
{
    const float* occ3   = (const float*)d_in[0];
    const int*   idx3   = (const int*)d_in[1];
    const float* occ5   = (const float*)d_in[2];
    const int*   idx5   = (const int*)d_in[3];
    const float* prev   = (const float*)d_in[4];
    const float* attn_W = (const float*)d_in[5];
    const float* attn_b = (const float*)d_in[6];
    const float* gate_W = (const float*)d_in[7];
    const float* gate_b = (const float*)d_in[8];

    const int N  = in_sizes[4] / D;
    const int E3 = in_sizes[1];
    const int E5 = in_sizes[3];
    const int E  = E3 + E5;

    // ws: keysb(bf16 N*D) | aggb(bf16 N*D) | row_start(N+1) | cnt(N) | bsum(1025) | rank(E) | edge_ids(E) | wta | wtg
    unsigned short* keysb = (unsigned short*)d_ws;
    unsigned int*   aggb  = (unsigned int*)(keysb + (size_t)N * D);
    int* row_start = (int*)((unsigned short*)aggb + (size_t)N * D);
    int* cnt       = row_start + (N + 1);
    int* bsum      = cnt + N;
    int* rank      = bsum + 1025;
    int* edge_ids  = rank + E;
    __bf16* wta    = (__bf16*)(edge_ids + E);
    __bf16* wtg    = wta + 128 * 128;

    float* out = (float*)d_out;

    (void)hipMemsetAsync(cnt, 0, (size_t)N * sizeof(int), stream);

    const int hblocks = (E + 255) / 256;
    hist_transpose_kernel<<<128 + hblocks, 256, 0, stream>>>(
        attn_W, gate_W, wta, wtg, idx3, idx5, cnt, rank, E3, E);

    const int nb = (N + 1023) / 1024;
    scan1_kernel  <<<nb, 256, 0, stream>>>(cnt, row_start, bsum, N);
    scan2_kernel  <<<1, 1024, 0, stream>>>(bsum, nb);
    scan3_kernel  <<<(N + 256) / 256, 256, 0, stream>>>(row_start, bsum, N, E);
    scatter_kernel<<<(E + 255) / 256, 256, 0, stream>>>(idx3, idx5, row_start, rank, edge_ids, E3, E);

    keys_mfma_kernel<<<(N + 63) / 64, 256, 0, stream>>>(prev, wta, attn_b, keysb, N);

    agg_kernel<<<(N + 3) / 4, 256, 0, stream>>>(occ3, occ5, keysb, row_start, edge_ids, aggb, E3, N);

    gate_mfma_kernel<<<(N + 63) / 64, 256, 0, stream>>>(prev, (const __bf16*)aggb, wtg, gate_b, out, N);
}

// Round 17
// 655.437 us; speedup vs baseline: 2.5160x; 1.0188x over previous
//
#include <hip/hip_runtime.h>
#include <math.h>

#define D 128
#define EPSF 1e-9f

typedef __bf16 bf16x8 __attribute__((ext_vector_type(8)));
typedef float  f32x4  __attribute__((ext_vector_type(4)));
typedef float  f32x2  __attribute__((ext_vector_type(2)));

static __device__ __forceinline__ float bf2f(unsigned short h) {
    union { unsigned int u; float f; } c; c.u = ((unsigned int)h) << 16;
    return c.f;
}
static __device__ __forceinline__ unsigned short f2bf(float f) {
    union { float f; unsigned int u; } c; c.f = f;
    unsigned int u = c.u + 0x7fffu + ((c.u >> 16) & 1u);
    return (unsigned short)(u >> 16);
}

// ---------------- fat kernel 1: W transpose (blocks 0..127) + histogram ----------------
__global__ __launch_bounds__(256) void hist_transpose_kernel(
    const float* __restrict__ attn_W, const float* __restrict__ gate_W,
    __bf16* __restrict__ wta, __bf16* __restrict__ wtg,
    const int* __restrict__ idx3, const int* __restrict__ idx5,
    int* __restrict__ cnt, int* __restrict__ rank, int E3, int E)
{
    int b = blockIdx.x;
    if (b < 128) {
        int i = b * 256 + threadIdx.x;          // i < 32768
        if (i < 128 * 128) {
            int k = i >> 7, n = i & 127;
            wta[n * 128 + k] = (__bf16)attn_W[i];
        }
        {   // gate_W is 256*128 = 32768 elements: every i valid
            int k = i >> 7, n = i & 127;
            wtg[n * 256 + k] = (__bf16)gate_W[i];
        }
    } else {
        int e = (b - 128) * 256 + threadIdx.x;
        if (e >= E) return;
        int n = (e < E3) ? idx3[e] : idx5[e - E3];
        rank[e] = atomicAdd(&cnt[n], 1);
    }
}

// ---------------- CSR scans ----------------
__global__ __launch_bounds__(256) void scan1_kernel(
    const int* __restrict__ cnt, int* __restrict__ row_start,
    int* __restrict__ bsum, int N)
{
    __shared__ int tsum[256];
    const int t = threadIdx.x;
    const int base = blockIdx.x * 1024;
    const int i0 = base + t * 4;
    int v0 = 0, v1 = 0, v2 = 0, v3 = 0;
    if (i0 + 0 < N) v0 = cnt[i0 + 0];
    if (i0 + 1 < N) v1 = cnt[i0 + 1];
    if (i0 + 2 < N) v2 = cnt[i0 + 2];
    if (i0 + 3 < N) v3 = cnt[i0 + 3];
    int s = v0 + v1 + v2 + v3;
    tsum[t] = s;
    __syncthreads();
    int val = s;
    for (int off = 1; off < 256; off <<= 1) {
        int tmp = (t >= off) ? tsum[t - off] : 0;
        __syncthreads();
        val += tmp; tsum[t] = val;
        __syncthreads();
    }
    int excl = val - s;
    if (i0 + 0 < N) row_start[i0 + 0] = excl;            excl += v0;
    if (i0 + 1 < N) row_start[i0 + 1] = excl;            excl += v1;
    if (i0 + 2 < N) row_start[i0 + 2] = excl;            excl += v2;
    if (i0 + 3 < N) row_start[i0 + 3] = excl;
    if (t == 255) bsum[blockIdx.x] = val;
}

__global__ __launch_bounds__(1024) void scan2_kernel(int* __restrict__ bsum, int nb)
{
    __shared__ int sh[1024];
    const int t = threadIdx.x;
    int v = (t < nb) ? bsum[t] : 0;
    sh[t] = v;
    __syncthreads();
    int val = v;
    for (int off = 1; off < 1024; off <<= 1) {
        int tmp = (t >= off) ? sh[t - off] : 0;
        __syncthreads();
        val += tmp; sh[t] = val;
        __syncthreads();
    }
    if (t < nb) bsum[t] = val - v;
}

__global__ __launch_bounds__(256) void scan3_kernel(
    int* __restrict__ row_start, const int* __restrict__ bsum, int N, int E)
{
    int i = blockIdx.x * 256 + threadIdx.x;
    if (i < N)       row_start[i] += bsum[i >> 10];
    else if (i == N) row_start[N] = E;
}

// ---------------- fat kernel 2: scatter (first sblocks) + keys MFMA ----------------
// independent stages: scatter needs row_start/rank (scan3 done); keys needs wta
// (fat kernel 1 done). Keys' MFMA waves fill issue slots while scatter's random
// 4B writes sit in the memory pipe.
__global__ __launch_bounds__(256) void scatter_keys_kernel(
    const int* __restrict__ idx3, const int* __restrict__ idx5,
    const int* __restrict__ row_start, const int* __restrict__ rank,
    int* __restrict__ edge_ids,
    const float* __restrict__ prev, const __bf16* __restrict__ wta,
    const float* __restrict__ attn_b, unsigned short* __restrict__ keysb,
    int E3, int E, int sblocks, int N)
{
    if ((int)blockIdx.x < sblocks) {
        int e = blockIdx.x * 256 + threadIdx.x;
        if (e >= E) return;
        int n = (e < E3) ? idx3[e] : idx5[e - E3];
        edge_ids[row_start[n] + rank[e]] = e;
        return;
    }

    __shared__ float stg[4][16 * D];    // 32 KB/block, wave-private slices
    const int kb_ = blockIdx.x - sblocks;
    const int lane = threadIdx.x & 63;
    const int wid  = threadIdx.x >> 6;
    const int m0 = (kb_ * 4 + wid) * 16;
    if (m0 >= N) return;
    const int lm = lane & 15;
    const int lg = lane >> 4;

    int arow = m0 + lm; if (arow >= N) arow = m0;
    const float* ap = prev + (size_t)arow * D + lg * 8;

    f32x4 acc[8] = {};
    #pragma unroll
    for (int kk = 0; kk < 4; ++kk) {
        float4 a0 = *(const float4*)(ap + kk * 32);
        float4 a1 = *(const float4*)(ap + kk * 32 + 4);
        bf16x8 af;
        af[0] = (__bf16)a0.x; af[1] = (__bf16)a0.y; af[2] = (__bf16)a0.z; af[3] = (__bf16)a0.w;
        af[4] = (__bf16)a1.x; af[5] = (__bf16)a1.y; af[6] = (__bf16)a1.z; af[7] = (__bf16)a1.w;
        const int k0 = kk * 32;
        #pragma unroll
        for (int t = 0; t < 8; ++t) {
            bf16x8 bf_ = *(const bf16x8*)(wta + (size_t)(t * 16 + lm) * 128 + k0 + lg * 8);
            acc[t] = __builtin_amdgcn_mfma_f32_16x16x32_bf16(af, bf_, acc[t], 0, 0, 0);
        }
    }

    float* kw = stg[wid];
    #pragma unroll
    for (int t = 0; t < 8; ++t) {
        float bcol = attn_b[t * 16 + lm];
        #pragma unroll
        for (int r = 0; r < 4; ++r)
            kw[(lg * 4 + r) * D + t * 16 + lm] = acc[t][r] + bcol;
    }
    // wave-private LDS: no barrier needed (lgkmcnt ordering within wave)
    #pragma unroll
    for (int q = 0; q < 8; ++q) {
        int idx = q * 64 + lane;
        int ro = idx >> 5;
        int co = (idx & 31) * 4;
        int row = m0 + ro;
        if (row < N) {
            f32x4 c = *(const f32x4*)&kw[ro * D + co];
            ushort4 o;
            o.x = f2bf(c[0]); o.y = f2bf(c[1]); o.z = f2bf(c[2]); o.w = f2bf(c[3]);
            *(ushort4*)(keysb + (size_t)row * D + co) = o;
        }
    }
}

// ---------------- per-node attention aggregate ----------------
// one 64-lane wave per node, lane owns dims 2l,2l+1 (8B gather/lane).
// ids preloaded lane-parallel + shfl broadcast; masked batches of 8 ->
// 8 independent gathers in flight. Minimal VGPR, no LDS (occupancy = lever).
__global__ __launch_bounds__(256) void agg_kernel(
    const float* __restrict__ occ3, const float* __restrict__ occ5,
    const unsigned short* __restrict__ keysb,
    const int* __restrict__ row_start, const int* __restrict__ edge_ids,
    unsigned int* __restrict__ aggb, int E3, int N)
{
    const int lane = threadIdx.x & 63;
    const int wid  = threadIdx.x >> 6;
    const int n = blockIdx.x * 4 + wid;
    if (n >= N) return;

    unsigned int kp = ((const unsigned int*)keysb)[(size_t)n * (D / 2) + lane];
    float kx = bf2f((unsigned short)(kp & 0xffffu));
    float ky = bf2f((unsigned short)(kp >> 16));

    const int rs = row_start[n];
    const int re = row_start[n + 1];
    const float scale = 0.0883883476483184f;   // 1/sqrt(128)

    float ax = 0.f, ay = 0.f, den = 0.f;

    for (int base = rs; base < re; base += 64) {
        const int left = re - base;
        const int cnt = left < 64 ? left : 64;
        int myid = (lane < cnt) ? edge_ids[base + lane] : 0;

        for (int j0 = 0; j0 < cnt; j0 += 8) {
            f32x2 v[8];
            #pragma unroll
            for (int j = 0; j < 8; ++j) {
                int e = __shfl(myid, j0 + j);
                const f32x2* vp = (e < E3)
                    ? (const f32x2*)(occ3 + (size_t)e * D)
                    : (const f32x2*)(occ5 + (size_t)(e - E3) * D);
                v[j] = __builtin_nontemporal_load(&vp[lane]);
            }
            float s[8];
            #pragma unroll
            for (int j = 0; j < 8; ++j)
                s[j] = v[j][0] * kx + v[j][1] * ky;
            #pragma unroll
            for (int sh = 32; sh >= 1; sh >>= 1) {
                #pragma unroll
                for (int j = 0; j < 8; ++j)
                    s[j] += __shfl_xor(s[j], sh);
            }
            #pragma unroll
            for (int j = 0; j < 8; ++j) {
                float ex = (j0 + j < cnt) ? __expf(s[j] * scale) : 0.f;
                den += ex;
                ax = fmaf(ex, v[j][0], ax);
                ay = fmaf(ex, v[j][1], ay);
            }
        }
    }

    float inv = 1.0f / (den + EPSF);
    unsigned int pack = (unsigned int)f2bf(ax * inv)
                      | ((unsigned int)f2bf(ay * inv) << 16);
    aggb[(size_t)n * (D / 2) + lane] = pack;
}

// ---------------- gate via MFMA ----------------
// epilogue re-layouts z through wave-private LDS -> coalesced f32x4 blend.
__global__ __launch_bounds__(256) void gate_mfma_kernel(
    const float* __restrict__ prev, const __bf16* __restrict__ aggb,
    const __bf16* __restrict__ wtg, const float* __restrict__ gate_b,
    float* __restrict__ out, int N)
{
    __shared__ float stg[4][16 * D];    // 32 KB/block, wave-private slices
    const int lane = threadIdx.x & 63;
    const int wid  = threadIdx.x >> 6;
    const int m0 = (blockIdx.x * 4 + wid) * 16;
    if (m0 >= N) return;
    const int lm = lane & 15;
    const int lg = lane >> 4;

    int arow = m0 + lm; if (arow >= N) arow = m0;
    const float*  aprev = prev + (size_t)arow * D + lg * 8;
    const __bf16* aagg  = aggb + (size_t)arow * D + lg * 8;

    f32x4 acc[8] = {};
    #pragma unroll
    for (int kk = 0; kk < 4; ++kk) {
        float4 a0 = *(const float4*)(aprev + kk * 32);
        float4 a1 = *(const float4*)(aprev + kk * 32 + 4);
        bf16x8 af;
        af[0] = (__bf16)a0.x; af[1] = (__bf16)a0.y; af[2] = (__bf16)a0.z; af[3] = (__bf16)a0.w;
        af[4] = (__bf16)a1.x; af[5] = (__bf16)a1.y; af[6] = (__bf16)a1.z; af[7] = (__bf16)a1.w;
        const int k0 = kk * 32;
        #pragma unroll
        for (int t = 0; t < 8; ++t) {
            bf16x8 bf_ = *(const bf16x8*)(wtg + (size_t)(t * 16 + lm) * 256 + k0 + lg * 8);
            acc[t] = __builtin_amdgcn_mfma_f32_16x16x32_bf16(af, bf_, acc[t], 0, 0, 0);
        }
    }
    #pragma unroll
    for (int kk = 0; kk < 4; ++kk) {
        bf16x8 af = *(const bf16x8*)(aagg + kk * 32);
        const int k0 = 128 + kk * 32;
        #pragma unroll
        for (int t = 0; t < 8; ++t) {
            bf16x8 bf_ = *(const bf16x8*)(wtg + (size_t)(t * 16 + lm) * 256 + k0 + lg * 8);
            acc[t] = __builtin_amdgcn_mfma_f32_16x16x32_bf16(af, bf_, acc[t], 0, 0, 0);
        }
    }

    float* zw = stg[wid];
    #pragma unroll
    for (int t = 0; t < 8; ++t) {
        float bcol = gate_b[t * 16 + lm];
        #pragma unroll
        for (int r = 0; r < 4; ++r)
            zw[(lg * 4 + r) * D + t * 16 + lm] = acc[t][r] + bcol;
    }
    // wave-private LDS: no barrier needed
    const unsigned short* aggu = (const unsigned short*)aggb;
    #pragma unroll
    for (int q = 0; q < 8; ++q) {
        int idx = q * 64 + lane;
        int ro = idx >> 5;
        int co = (idx & 31) * 4;
        int row = m0 + ro;
        if (row < N) {
            size_t off = (size_t)row * D + co;
            f32x4 c = *(const f32x4*)&zw[ro * D + co];
            f32x4 p = *(const f32x4*)(prev + off);
            ushort4 a4 = *(const ushort4*)(aggu + off);
            f32x4 o;
            float z;
            z = 1.0f / (1.0f + __expf(-c[0])); o[0] = fmaf(z, bf2f(a4.x) - p[0], p[0]);
            z = 1.0f / (1.0f + __expf(-c[1])); o[1] = fmaf(z, bf2f(a4.y) - p[1], p[1]);
            z = 1.0f / (1.0f + __expf(-c[2])); o[2] = fmaf(z, bf2f(a4.z) - p[2], p[2]);
            z = 1.0f / (1.0f + __expf(-c[3])); o[3] = fmaf(z, bf2f(a4.w) - p[3], p[3]);
            __builtin_nontemporal_store(o, (f32x4*)(out + off));
        }
    }
}

extern "C" void kernel_launch(void* const* d_in, const int* in_sizes, int n_in,
                              void* d_out, int out_size, void* d_ws, size_t ws_size,
                              hipStream_t stream)
{
    const float* occ3   = (const float*)d_in[0];
    const int*   idx3   = (const int*)d_in[1];
    const float* occ5   = (const float*)d_in[2];
    const int*   idx5   = (const int*)d_in[3];
    const float* prev   = (const float*)d_in[4];
    const float* attn_W = (const float*)d_in[5];
    const float* attn_b = (const float*)d_in[6];
    const float* gate_W = (const float*)d_in[7];
    const float* gate_b = (const float*)d_in[8];

    const int N  = in_sizes[4] / D;
    const int E3 = in_sizes[1];
    const int E5 = in_sizes[3];
    const int E  = E3 + E5;

    // ws: keysb(bf16 N*D) | aggb(bf16 N*D) | row_start(N+1) | cnt(N) | bsum(1025) | rank(E) | edge_ids(E) | wta | wtg
    unsigned short* keysb = (unsigned short*)d_ws;
    unsigned int*   aggb  = (unsigned int*)(keysb + (size_t)N * D);
    int* row_start = (int*)((unsigned short*)aggb + (size_t)N * D);
    int* cnt       = row_start + (N + 1);
    int* bsum      = cnt + N;
    int* rank      = bsum + 1025;
    int* edge_ids  = rank + E;
    __bf16* wta    = (__bf16*)(edge_ids + E);
    __bf16* wtg    = wta + 128 * 128;

    float* out = (float*)d_out;

    (void)hipMemsetAsync(cnt, 0, (size_t)N * sizeof(int), stream);

    const int hblocks = (E + 255) / 256;
    hist_transpose_kernel<<<128 + hblocks, 256, 0, stream>>>(
        attn_W, gate_W, wta, wtg, idx3, idx5, cnt, rank, E3, E);

    const int nb = (N + 1023) / 1024;
    scan1_kernel<<<nb, 256, 0, stream>>>(cnt, row_start, bsum, N);
    scan2_kernel<<<1, 1024, 0, stream>>>(bsum, nb);
    scan3_kernel<<<(N + 256) / 256, 256, 0, stream>>>(row_start, bsum, N, E);

    const int sblocks = (E + 255) / 256;
    const int kblocks = (N + 63) / 64;
    scatter_keys_kernel<<<sblocks + kblocks, 256, 0, stream>>>(
        idx3, idx5, row_start, rank, edge_ids,
        prev, wta, attn_b, keysb, E3, E, sblocks, N);

    agg_kernel<<<(N + 3) / 4, 256, 0, stream>>>(occ3, occ5, keysb, row_start, edge_ids, aggb, E3, N);

    gate_mfma_kernel<<<(N + 63) / 64, 256, 0, stream>>>(prev, (const __bf16*)aggb, wtg, gate_b, out, N);
}